// Round 2
// baseline (860.414 us; speedup 1.0000x reference)
//
#include <hip/hip_runtime.h>

typedef unsigned short u16;
typedef unsigned int   u32;

typedef __attribute__((ext_vector_type(8))) short bf16x8;
typedef __attribute__((ext_vector_type(4))) float f32x4;

__device__ __forceinline__ u16 f2bf(float f) {
  u32 u = __float_as_uint(f);
  u32 r = (u + 0x7fffu + ((u >> 16) & 1u)) >> 16;
  return (u16)r;
}

__device__ __forceinline__ void async16(const void* g, void* l) {
  __builtin_amdgcn_global_load_lds(
      (const __attribute__((address_space(1))) u32*)g,
      (__attribute__((address_space(3))) u32*)l, 16, 0, 0);
}

// ---------------------------------------------------------------------------
// conv1 (1x1, 512->64) + BN + leaky + reorg, writes in_bf channels [0,256)
// one thread per (b,h,w) of 38x38; all 64 oc in registers; w1 chunks in LDS
// ---------------------------------------------------------------------------
__global__ __launch_bounds__(256) void conv1_reorg_kern(
    const float* __restrict__ stage5, const float* __restrict__ w1,
    const float* __restrict__ g1, const float* __restrict__ b1,
    const float* __restrict__ m1, const float* __restrict__ v1,
    u16* __restrict__ in_bf)
{
  __shared__ float wlds[64][68];   // [ic_local][oc], pad 68 keeps float4 16B-aligned
  __shared__ float2 bn[64];
  const int t = threadIdx.x;
  int m = blockIdx.x * 256 + t;
  bool valid = (m < 46208);
  int mm = valid ? m : 46207;
  int b = mm / 1444;
  int hw = mm - b * 1444;
  const float* src = stage5 + (size_t)b * (512 * 1444) + hw;
  if (t < 64) {
    float sc = g1[t] * rsqrtf(v1[t] + 1e-5f);
    bn[t].x = sc;
    bn[t].y = b1[t] - m1[t] * sc;
  }
  float acc[64];
#pragma unroll
  for (int i = 0; i < 64; ++i) acc[i] = 0.f;

  for (int ic0 = 0; ic0 < 512; ic0 += 64) {
    __syncthreads();
#pragma unroll
    for (int r = 0; r < 16; ++r) {
      int idx = r * 256 + t;          // = oc*64 + icl : coalesced w1 rows
      int oc = idx >> 6, icl = idx & 63;
      wlds[icl][oc] = w1[(size_t)oc * 512 + ic0 + icl];
    }
    __syncthreads();
    for (int g = 0; g < 4; ++g) {
      float av[16];
#pragma unroll
      for (int u = 0; u < 16; ++u)
        av[u] = src[(size_t)(ic0 + g * 16 + u) * 1444];
#pragma unroll
      for (int u = 0; u < 16; ++u) {
#pragma unroll
        for (int o4 = 0; o4 < 16; ++o4) {
          float4 wv = *(const float4*)&wlds[g * 16 + u][o4 * 4];
          acc[o4 * 4 + 0] += av[u] * wv.x;
          acc[o4 * 4 + 1] += av[u] * wv.y;
          acc[o4 * 4 + 2] += av[u] * wv.z;
          acc[o4 * 4 + 3] += av[u] * wv.w;
        }
      }
    }
  }
  if (valid) {
    int h = hw / 38, wq = hw - h * 38;
    int ho = h >> 1, wo = wq >> 1, q = ((h & 1) << 1) | (wq & 1);
    u16* dst = in_bf + (((size_t)b * 21 + 1 + ho) * 21 + 1 + wo) * 1280 + q * 64;
#pragma unroll
    for (int gg = 0; gg < 16; ++gg) {
      int oc = gg * 4;
      float v0 = acc[oc + 0] * bn[oc + 0].x + bn[oc + 0].y;
      float v1 = acc[oc + 1] * bn[oc + 1].x + bn[oc + 1].y;
      float v2 = acc[oc + 2] * bn[oc + 2].x + bn[oc + 2].y;
      float v3 = acc[oc + 3] * bn[oc + 3].x + bn[oc + 3].y;
      v0 = v0 > 0.f ? v0 : 0.1f * v0;
      v1 = v1 > 0.f ? v1 : 0.1f * v1;
      v2 = v2 > 0.f ? v2 : 0.1f * v2;
      v3 = v3 > 0.f ? v3 : 0.1f * v3;
      u32 lo = (u32)f2bf(v0) | ((u32)f2bf(v1) << 16);
      u32 hi = (u32)f2bf(v2) | ((u32)f2bf(v3) << 16);
      u32* dp = (u32*)(dst + oc);
      dp[0] = lo; dp[1] = hi;
    }
  }
}

// ---------------------------------------------------------------------------
// stage6 NCHW -> in_bf NHWC channels [256,1280), bf16, LDS-tiled transpose
// grid (6 ij-tiles, 16 c-tiles, 32 b)
// tile stored as tile[channel_local][ij_local]; store phase must read
// tile[col=channel][ijl=ij]  (round-1 bug: was tile[ijl][col] == transposed)
// ---------------------------------------------------------------------------
__global__ __launch_bounds__(256) void fill_stage6_kern(
    const float* __restrict__ s6, u16* __restrict__ in_bf)
{
  __shared__ u16 tile[64][66];
  const int t = threadIdx.x;
  const int jt = blockIdx.x, ct = blockIdx.y, b = blockIdx.z;
  const int ij0 = jt * 64, c0 = ct * 64;
  const int col = t & 63, rr = t >> 6;
#pragma unroll
  for (int r = 0; r < 16; ++r) {
    int cl = r * 4 + rr;
    int ij = ij0 + col;
    float v = 0.f;
    if (ij < 361) v = s6[((size_t)b * 1024 + c0 + cl) * 361 + ij];
    tile[cl][col] = f2bf(v);
  }
  __syncthreads();
#pragma unroll
  for (int r = 0; r < 16; ++r) {
    int ijl = r * 4 + rr;
    int ij = ij0 + ijl;
    if (ij < 361) {
      int i = ij / 19, j = ij - i * 19;
      in_bf[(((size_t)b * 21 + 1 + i) * 21 + 1 + j) * 1280 + 256 + c0 + col] =
          tile[col][ijl];   // channel=col, ij=ijl
    }
  }
}

// ---------------------------------------------------------------------------
// w2 (1024,1280,3,3) fp32 -> w2bf[oc][khw*1280+ic] bf16, BN scale folded
// ---------------------------------------------------------------------------
__global__ __launch_bounds__(256) void prep_w2_kern(
    const float* __restrict__ w2, const float* __restrict__ g2,
    const float* __restrict__ v2, u16* __restrict__ w2bf)
{
  int idx = blockIdx.x * 256 + threadIdx.x;   // exactly 11796480 threads
  int oc = idx / 11520;
  int k = idx - oc * 11520;
  int khw = k / 1280;
  int ic = k - khw * 1280;
  float sc = g2[oc] * rsqrtf(v2[oc] + 1e-5f);
  w2bf[idx] = f2bf(w2[((size_t)oc * 1280 + ic) * 9 + khw] * sc);
}

// ---------------------------------------------------------------------------
// meta_state -> cls_w bf16 [600][1024], cls_b fp32 [600]; shift2 fp32 [1024]
// ---------------------------------------------------------------------------
__global__ __launch_bounds__(256) void prep_small_kern(
    const float* __restrict__ meta, const float* __restrict__ g2,
    const float* __restrict__ b2, const float* __restrict__ m2,
    const float* __restrict__ v2, u16* __restrict__ clsw,
    float* __restrict__ clsb, float* __restrict__ shift2)
{
  int idx = blockIdx.x * 256 + threadIdx.x;   // exactly 614400 threads
  int cm = idx >> 10, k = idx & 1023;
  clsw[idx] = f2bf(meta[(size_t)cm * 1025 + k]);
  if (idx < 600) clsb[idx] = meta[(size_t)idx * 1025 + 1024];
  if (idx < 1024) {
    float sc = g2[idx] * rsqrtf(v2[idx] + 1e-5f);
    shift2[idx] = b2[idx] - m2[idx] * sc;
  }
}

// ---------------------------------------------------------------------------
// conv2: implicit GEMM, A=weights[1024][11520], B=input rows (halo via padded
// NHWC buffer). 128(oc) x 128(m) x 32 tiles, 4 waves, 16x16x32 bf16 MFMA.
// Epilogue: +shift2, leaky, write pre[m][oc] bf16.
// ---------------------------------------------------------------------------
__global__ __launch_bounds__(256) void conv2_gemm_kern(
    const u16* __restrict__ Wg, const u16* __restrict__ Ig,
    const float* __restrict__ shift2, u16* __restrict__ pre)
{
  __shared__ u16 Wa[128 * 32];
  __shared__ u16 Ib[128 * 32];
  __shared__ float shft[128];
  const int t = threadIdx.x;
  const int w = t >> 6, lane = t & 63;
  const int m0 = blockIdx.x * 128;
  const int oc0 = blockIdx.y * 128;

  if (t < 128) shft[t] = shift2[oc0 + t];

  const int rpart = (t & 3) * 8;   // element offset inside 32-wide k row
  const int rw = t >> 2;           // row 0..63
  const u16* pW0 = Wg + (size_t)(oc0 + rw) * 11520 + rpart;
  const u16* pW1 = pW0 + (size_t)64 * 11520;

  int mA = m0 + rw;       if (mA > 11551) mA = 11551;
  int mB = m0 + 64 + rw;  if (mB > 11551) mB = 11551;
  int bA = mA / 361, ijA = mA - bA * 361;
  int ohA = ijA / 19, owA = ijA - ohA * 19;
  int bB = mB / 361, ijB = mB - bB * 361;
  int ohB = ijB / 19, owB = ijB - ohB * 19;
  const u16* pI0 = Ig + (size_t)((bA * 21 + ohA) * 21 + owA) * 1280 + rpart;
  const u16* pI1 = Ig + (size_t)((bB * 21 + ohB) * 21 + owB) * 1280 + rpart;

  u16* waS0 = &Wa[(w * 64) * 8];
  u16* waS1 = &Wa[(256 + w * 64) * 8];
  u16* ibS0 = &Ib[(w * 64) * 8];
  u16* ibS1 = &Ib[(256 + w * 64) * 8];

  const int aBase = ((w >> 1) * 64 + (lane & 15)) * 32 + (lane >> 4) * 8;
  const int bBase = ((w & 1) * 64 + (lane & 15)) * 32 + (lane >> 4) * 8;

  f32x4 acc[4][4] = {};

  for (int khw = 0; khw < 9; ++khw) {
    const int kh = khw / 3, kw = khw - kh * 3;
    const size_t iOffB = (size_t)(kh * 21 + kw) * 1280;
    const size_t wOffB = (size_t)khw * 1280;
    for (int icc = 0; icc < 40; ++icc) {
      const size_t io = iOffB + (size_t)icc * 32;
      const size_t wo_ = wOffB + (size_t)icc * 32;
      async16(pW0 + wo_, waS0);
      async16(pW1 + wo_, waS1);
      async16(pI0 + io, ibS0);
      async16(pI1 + io, ibS1);
      __syncthreads();
      bf16x8 af[4], bfv[4];
#pragma unroll
      for (int i = 0; i < 4; ++i)
        af[i] = *(const bf16x8*)&Wa[aBase + i * (16 * 32)];
#pragma unroll
      for (int j = 0; j < 4; ++j)
        bfv[j] = *(const bf16x8*)&Ib[bBase + j * (16 * 32)];
#pragma unroll
      for (int i = 0; i < 4; ++i)
#pragma unroll
        for (int j = 0; j < 4; ++j)
          acc[i][j] = __builtin_amdgcn_mfma_f32_16x16x32_bf16(
              af[i], bfv[j], acc[i][j], 0, 0, 0);
      __syncthreads();
    }
  }

  const int aRow = (w >> 1) * 64, bRow = (w & 1) * 64;
  const int lq = lane >> 4, lr = lane & 15;
#pragma unroll
  for (int j = 0; j < 4; ++j) {
    int m = m0 + bRow + j * 16 + lr;
    if (m >= 11552) continue;
    u16* prow = pre + (size_t)m * 1024 + oc0;
#pragma unroll
    for (int i = 0; i < 4; ++i) {
      int ocl = aRow + i * 16 + lq * 4;
      float v0 = acc[i][j][0] + shft[ocl + 0]; v0 = v0 > 0.f ? v0 : 0.1f * v0;
      float v1 = acc[i][j][1] + shft[ocl + 1]; v1 = v1 > 0.f ? v1 : 0.1f * v1;
      float v2 = acc[i][j][2] + shft[ocl + 2]; v2 = v2 > 0.f ? v2 : 0.1f * v2;
      float v3 = acc[i][j][3] + shft[ocl + 3]; v3 = v3 > 0.f ? v3 : 0.1f * v3;
      u32 lo = (u32)f2bf(v0) | ((u32)f2bf(v1) << 16);
      u32 hi = (u32)f2bf(v2) | ((u32)f2bf(v3) << 16);
      u32* dp = (u32*)(prow + ocl);
      dp[0] = lo; dp[1] = hi;
    }
  }
}

// ---------------------------------------------------------------------------
// einsum: GEMM A=cls_w[600][1024], B=pre[11552][1024]; out fp32 + bias,
// scatter to (b, cm, ij) layout.
// ---------------------------------------------------------------------------
__global__ __launch_bounds__(256) void einsum_gemm_kern(
    const u16* __restrict__ Ag, const u16* __restrict__ Bg,
    const float* __restrict__ biasg, float* __restrict__ out)
{
  __shared__ u16 Wa[128 * 32];
  __shared__ u16 Ib[128 * 32];
  __shared__ float sbias[128];
  const int t = threadIdx.x;
  const int w = t >> 6, lane = t & 63;
  const int m0 = blockIdx.x * 128;
  const int cm0 = blockIdx.y * 128;
  if (t < 128) { int c = cm0 + t; sbias[t] = (c < 600) ? biasg[c] : 0.f; }

  const int rpart = (t & 3) * 8;
  const int rw = t >> 2;
  int rA0 = cm0 + rw;       if (rA0 > 599) rA0 = 599;
  int rA1 = cm0 + 64 + rw;  if (rA1 > 599) rA1 = 599;
  int rB0 = m0 + rw;        if (rB0 > 11551) rB0 = 11551;
  int rB1 = m0 + 64 + rw;   if (rB1 > 11551) rB1 = 11551;
  const u16* pA0 = Ag + (size_t)rA0 * 1024 + rpart;
  const u16* pA1 = Ag + (size_t)rA1 * 1024 + rpart;
  const u16* pB0 = Bg + (size_t)rB0 * 1024 + rpart;
  const u16* pB1 = Bg + (size_t)rB1 * 1024 + rpart;

  u16* waS0 = &Wa[(w * 64) * 8];
  u16* waS1 = &Wa[(256 + w * 64) * 8];
  u16* ibS0 = &Ib[(w * 64) * 8];
  u16* ibS1 = &Ib[(256 + w * 64) * 8];

  const int aBase = ((w >> 1) * 64 + (lane & 15)) * 32 + (lane >> 4) * 8;
  const int bBase = ((w & 1) * 64 + (lane & 15)) * 32 + (lane >> 4) * 8;

  f32x4 acc[4][4] = {};

  for (int kt = 0; kt < 32; ++kt) {
    const size_t off = (size_t)kt * 32;
    async16(pA0 + off, waS0);
    async16(pA1 + off, waS1);
    async16(pB0 + off, ibS0);
    async16(pB1 + off, ibS1);
    __syncthreads();
    bf16x8 af[4], bfv[4];
#pragma unroll
    for (int i = 0; i < 4; ++i)
      af[i] = *(const bf16x8*)&Wa[aBase + i * (16 * 32)];
#pragma unroll
    for (int j = 0; j < 4; ++j)
      bfv[j] = *(const bf16x8*)&Ib[bBase + j * (16 * 32)];
#pragma unroll
    for (int i = 0; i < 4; ++i)
#pragma unroll
      for (int j = 0; j < 4; ++j)
        acc[i][j] = __builtin_amdgcn_mfma_f32_16x16x32_bf16(
            af[i], bfv[j], acc[i][j], 0, 0, 0);
    __syncthreads();
  }

  const int aRow = (w >> 1) * 64, bRow = (w & 1) * 64;
  const int lq = lane >> 4, lr = lane & 15;
#pragma unroll
  for (int j = 0; j < 4; ++j) {
    int m = m0 + bRow + j * 16 + lr;
    if (m >= 11552) continue;
    int b = m / 361, ij = m - b * 361;
    float* obase = out + (size_t)b * 216600 + ij;
#pragma unroll
    for (int i = 0; i < 4; ++i) {
      int cml = aRow + i * 16 + lq * 4;
#pragma unroll
      for (int r = 0; r < 4; ++r) {
        int cm = cm0 + cml + r;
        if (cm < 600) obase[(size_t)cm * 361] = acc[i][j][r] + sbias[cml + r];
      }
    }
  }
}

// ---------------------------------------------------------------------------
// launch
// ---------------------------------------------------------------------------
extern "C" void kernel_launch(void* const* d_in, const int* in_sizes, int n_in,
                              void* d_out, int out_size, void* d_ws, size_t ws_size,
                              hipStream_t stream)
{
  const float* stage6 = (const float*)d_in[0];
  const float* stage5 = (const float*)d_in[1];
  const float* w1 = (const float*)d_in[2];
  const float* g1 = (const float*)d_in[3];
  const float* b1 = (const float*)d_in[4];
  const float* m1 = (const float*)d_in[5];
  const float* v1 = (const float*)d_in[6];
  const float* w2 = (const float*)d_in[7];
  const float* g2 = (const float*)d_in[8];
  const float* b2 = (const float*)d_in[9];
  const float* m2 = (const float*)d_in[10];
  const float* v2 = (const float*)d_in[11];
  const float* meta = (const float*)d_in[12];
  float* out = (float*)d_out;

  char* ws = (char*)d_ws;
  u16*   in_bf  = (u16*)(ws);                  // 36,126,720 B  (32*21*21*1280 bf16)
  u16*   w2bf   = (u16*)(ws + 36126720);       // 23,592,960 B  (1024*11520 bf16)
  u16*   prebf  = (u16*)(ws + 59719680);       // 23,658,496 B  (11552*1024 bf16)
  u16*   clsw   = (u16*)(ws + 83378176);       //  1,228,800 B  (600*1024 bf16)
  float* clsb   = (float*)(ws + 84606976);     //      2,560 B
  float* shift2 = (float*)(ws + 84609536);     //      4,096 B   total ~84.6 MB

  hipMemsetAsync(in_bf, 0, 36126720, stream);  // zero border = conv2 padding
  prep_w2_kern<<<46080, 256, 0, stream>>>(w2, g2, v2, w2bf);
  prep_small_kern<<<2400, 256, 0, stream>>>(meta, g2, b2, m2, v2, clsw, clsb, shift2);
  conv1_reorg_kern<<<181, 256, 0, stream>>>(stage5, w1, g1, b1, m1, v1, in_bf);
  fill_stage6_kern<<<dim3(6, 16, 32), 256, 0, stream>>>(stage6, in_bf);
  conv2_gemm_kern<<<dim3(91, 8), 256, 0, stream>>>(w2bf, in_bf, shift2, prebf);
  einsum_gemm_kern<<<dim3(91, 5), 256, 0, stream>>>(clsw, prebf, clsb, out);
}